// Round 2
// baseline (541.007 us; speedup 1.0000x reference)
//
#include <hip/hip_runtime.h>

// ChaosModulator: per-(b,c) nonlinear recurrence over t (b*c=16384, t=4096).
//   sigma = 3.5*z*(1-z) + 0.5*x_t
//   z'    = 0.5*z + 0.5*sigmoid(2*sigma)    (tanh form; clip is a no-op)
//   u_t   = 0.5*x_t + z' - 0.5
//
// R2: LDS-transposed tiling. 256 blocks x 64 threads (1 wave/CU, 1 seq/lane).
// Tile = 64 rows x 128 t (32 KiB LDS), XOR-swizzled float4 groups so both
// the row-burst staging (2 rows x 512B contiguous per instr) and the
// lane-sequential compute reads run at pure LDS bandwidth. u overwrites x
// in-place in the tile; stores go out row-burst coalesced.
// Register double-buffer (32 float4) prefetches tile k+1 during compute.

#define SEQ_T 4096
#define TT    128            // t per tile
#define NT    (SEQ_T / TT)   // 32 tiles
#define NG    (TT / 4)       // 32 float4 groups per row
#define ROWS  64

__device__ __forceinline__ void chaos_step(float& z, float xs, float& us) {
    const float CA = -10.098865286222744f;  // 3.5 * (-2*log2(e))
    const float CB = -1.4426950408889634f;  // 0.5 * (-2*log2(e))
    float p  = CB * xs;                          // off-chain
    float hz = 0.5f * z;                         // parallel path
    float zz = __builtin_fmaf(-z, z, z);         // z - z^2          (chain)
    float s  = __builtin_fmaf(CA, zz, p);        // -2*log2e*sigma   (chain)
    float e  = __builtin_amdgcn_exp2f(s);        // v_exp_f32        (chain)
    float r  = __builtin_amdgcn_rcpf(e + 1.0f);  // sigmoid(2*sigma) (chain)
    z  = __builtin_fmaf(0.5f, r, hz);            // z'               (chain)
    us = __builtin_fmaf(0.5f, xs, z - 0.5f);     // u (off-chain)
}

__global__ __launch_bounds__(64, 1)
void ChaosModulator_28922309771717_kernel(const float* __restrict__ x,
                                          const float* __restrict__ z0,
                                          float* __restrict__ u) {
    __shared__ __align__(16) float lds[ROWS * TT];   // 32 KiB

    const int L = threadIdx.x;         // lane 0..63
    const int seqbase = blockIdx.x * ROWS;
    const int rhi = L >> 5;            // 0..1 : row-within-pair for staging
    const int gw  = L & 31;            // col group for staging
    const int sw  = L & 7;             // compute-phase swizzle key

    const float* __restrict__ xb = x + (size_t)seqbase * SEQ_T;
    float* __restrict__ ub       = u + (size_t)seqbase * SEQ_T;

    float4 pf[NG];
    // prefetch tile 0: instr i covers rows {2i, 2i+1}, 512 B contiguous each
#pragma unroll
    for (int i = 0; i < NG; ++i) {
        int r = 2 * i + rhi;
        pf[i] = *(const float4*)(xb + (size_t)r * SEQ_T + gw * 4);
    }

    float z = z0[seqbase + L];

    for (int k = 0; k < NT; ++k) {
        // ---- stage tile k: regs -> LDS (swizzled) ----
#pragma unroll
        for (int i = 0; i < NG; ++i) {
            int r = 2 * i + rhi;
            *(float4*)&lds[r * TT + ((gw ^ (r & 7)) << 2)] = pf[i];
        }
        __syncthreads();

        // ---- prefetch tile k+1 (consumed next iter; ~4000 cyc to cover) ----
        if (k + 1 < NT) {
#pragma unroll
            for (int i = 0; i < NG; ++i) {
                int r = 2 * i + rhi;
                pf[i] = *(const float4*)(xb + (size_t)r * SEQ_T + (k + 1) * TT + gw * 4);
            }
        }

        // ---- compute 128 steps on own row, u in-place ----
#pragma unroll
        for (int g = 0; g < NG; ++g) {
            float* p = &lds[L * TT + ((g ^ sw) << 2)];
            float4 xq = *(float4*)p;
            float4 uq;
            chaos_step(z, xq.x, uq.x);
            chaos_step(z, xq.y, uq.y);
            chaos_step(z, xq.z, uq.z);
            chaos_step(z, xq.w, uq.w);
            *(float4*)p = uq;
        }
        __syncthreads();

        // ---- store tile k: LDS -> global, row-burst coalesced ----
#pragma unroll
        for (int i = 0; i < NG; ++i) {
            int r = 2 * i + rhi;
            float4 uq = *(const float4*)&lds[r * TT + ((gw ^ (r & 7)) << 2)];
            *(float4*)(ub + (size_t)r * SEQ_T + k * TT + gw * 4) = uq;
        }
        // no barrier here: next stage writes the exact same per-lane LDS
        // addresses this phase read; DS ops are in-order within a wave.
    }
}

extern "C" void kernel_launch(void* const* d_in, const int* in_sizes, int n_in,
                              void* d_out, int out_size, void* d_ws, size_t ws_size,
                              hipStream_t stream) {
    const float* x  = (const float*)d_in[0];   // (32, 512, 4096)
    const float* z0 = (const float*)d_in[1];   // (32, 512)
    float* uo = (float*)d_out;                 // (32, 512, 4096)

    const int n_seq = in_sizes[1];             // 16384
    dim3 grid(n_seq / ROWS), block(ROWS);
    ChaosModulator_28922309771717_kernel<<<grid, block, 0, stream>>>(x, z0, uo);
}